// Round 2
// baseline (169.598 us; speedup 1.0000x reference)
//
#include <hip/hip_runtime.h>

// Hierarchical sparse attention (binary tree), MI355X gfx950.
// B=4, S=4096, H=8, D=64, f32.
//
// v3: two kernels.
//  K1 chunk_root: per (bh, 64-leaf chunk) build levels 1..6 in LDS, write
//     ONLY the level-6 chunk root to global (512 KB total per tensor).
//  K2 attn_fused: per (bh, chunk) block:
//     - load the 64 chunk roots (32 KB, L2-resident) into LDS
//     - in-place strided binary reduction builds levels 7..11 redundantly;
//       the 6 path nodes (levels 6..11) are extracted into REGISTERS
//     - the same 32 KB LDS is then reused for the in-chunk tree levels 1..5
//     - scoring with 2-query unroll for ILP
//  This deletes the 32-block build_hi kernel (serialization) and one launch
//  gap, drops LDS 34816->32768, and moves path nodes LDS->VGPR.

#define S 4096
#define H 8
#define D 64
#define B 4
#define NBH 32
#define SCALE 0.125f

__device__ inline float red16(float x) {
    x += __shfl_xor(x, 1);
    x += __shfl_xor(x, 2);
    x += __shfl_xor(x, 4);
    x += __shfl_xor(x, 8);
    return x;
}

__device__ inline float dot4(const float4 a, const float4 b) {
    return a.x * b.x + a.y * b.y + a.z * b.z + a.w * b.w;
}

// parent(k,v) from two children: softmax-weighted merge (16-lane reduce).
__device__ inline void combine(const float4 k0, const float4 k1,
                               const float4 v0, const float4 v1,
                               float4& kp, float4& vp) {
    kp.x = 0.5f * (k0.x + k1.x);
    kp.y = 0.5f * (k0.y + k1.y);
    kp.z = 0.5f * (k0.z + k1.z);
    kp.w = 0.5f * (k0.w + k1.w);
    float pss = red16(dot4(kp, kp)) * SCALE;
    float p0  = red16(dot4(kp, k0)) * SCALE;
    float p1  = red16(dot4(kp, k1)) * SCALE;
    float m  = fmaxf(pss, fmaxf(p0, p1));
    float es = __expf(pss - m), e0 = __expf(p0 - m), e1 = __expf(p1 - m);
    float inv = 1.0f / (es + e0 + e1 + 1e-9f);
    float h = 0.5f * es;
    vp.x = ((h + e0) * v0.x + (h + e1) * v1.x) * inv;
    vp.y = ((h + e0) * v0.y + (h + e1) * v1.y) * inv;
    vp.z = ((h + e0) * v0.z + (h + e1) * v1.z) * inv;
    vp.w = ((h + e0) * v0.w + (h + e1) * v1.w) * inv;
}

// K1: per (bh, 64-leaf chunk) build levels 1..6 in LDS; write ONLY the
// chunk root (level-6 node) to global at row (bh*64 + c).
__global__ __launch_bounds__(256) void chunk_root(
    const float* __restrict__ k, const float* __restrict__ v,
    float* __restrict__ khi, float* __restrict__ vhi)
{
    __shared__ float lkA[32 * 64], lvA[32 * 64];
    __shared__ float lkB[16 * 64], lvB[16 * 64];
    const int t = threadIdx.x;
    const int sub = t & 15;
    const int pg = t >> 4;
    const int blk = blockIdx.x;
    const int c = blk & 63;
    const int bh = blk >> 6;
    const int b = bh >> 3, h = bh & 7;

#pragma unroll
    for (int r = 0; r < 2; ++r) {
        int j = pg + r * 16;
        int s0 = c * 64 + 2 * j;
        size_t a0 = ((((size_t)b * S + s0) * H + h) * D) + sub * 4;
        float4 k0 = *(const float4*)(k + a0);
        float4 k1 = *(const float4*)(k + a0 + H * D);
        float4 v0 = *(const float4*)(v + a0);
        float4 v1 = *(const float4*)(v + a0 + H * D);
        float4 kp, vp;
        combine(k0, k1, v0, v1, kp, vp);
        *(float4*)(lkA + j * 64 + sub * 4) = kp;
        *(float4*)(lvA + j * 64 + sub * 4) = vp;
    }
    __syncthreads();

    float *sk = lkA, *sv = lvA, *dk = lkB, *dv = lvB;
#pragma unroll
    for (int l = 2; l <= 6; ++l) {
        int np = 64 >> l;            // 16,8,4,2,1
        if (pg < np) {
            int j = pg;
            float4 k0 = *(const float4*)(sk + (2 * j) * 64 + sub * 4);
            float4 k1 = *(const float4*)(sk + (2 * j + 1) * 64 + sub * 4);
            float4 v0 = *(const float4*)(sv + (2 * j) * 64 + sub * 4);
            float4 v1 = *(const float4*)(sv + (2 * j + 1) * 64 + sub * 4);
            float4 kp, vp;
            combine(k0, k1, v0, v1, kp, vp);
            if (l < 6) {
                *(float4*)(dk + j * 64 + sub * 4) = kp;
                *(float4*)(dv + j * 64 + sub * 4) = vp;
            } else {
                size_t g = ((size_t)bh * 64 + c) * 64 + sub * 4;
                *(float4*)(khi + g) = kp;
                *(float4*)(vhi + g) = vp;
            }
        }
        __syncthreads();
        float* tp;
        tp = sk; sk = dk; dk = tp;
        tp = sv; sv = dv; dv = tp;
    }
}

// K2: fused hi-tree + attention. Block = (bh, chunk of 64 queries).
__global__ __launch_bounds__(256, 4) void attn_fused(
    const float* __restrict__ q, const float* __restrict__ k,
    const float* __restrict__ v,
    const float* __restrict__ khi, const float* __restrict__ vhi,
    float* __restrict__ out)
{
    __shared__ float rk[64 * 64], rv[64 * 64];   // 16 KB each; reused as tree
    const int t = threadIdx.x;
    const int sub = t & 15;
    const int pg = t >> 4;
    const int blk = blockIdx.x;
    const int c = blk & 63;
    const int bh = blk >> 6;
    const int b = bh >> 3, h = bh & 7;

    // ---- Phase A: load the 64 chunk roots for this bh (32 KB, L2-hot) ----
    {
        size_t base = (size_t)bh * 64 * 64;
        for (int i = t; i < 1024; i += 256) {
            *(float4*)(rk + i * 4) = *(const float4*)(khi + base + i * 4);
            *(float4*)(rv + i * 4) = *(const float4*)(vhi + base + i * 4);
        }
    }
    __syncthreads();

    // ---- Phase B: in-place strided reduction, extract path nodes 6..11 ----
    // After step t, level-(6+t) node j lives at row (j << t).
    float4 pkr[6], pvr[6];
    pkr[0] = *(const float4*)(rk + (c ^ 1) * 64 + sub * 4);
    pvr[0] = *(const float4*)(rv + (c ^ 1) * 64 + sub * 4);
    __syncthreads();

#pragma unroll
    for (int tt = 1; tt <= 5; ++tt) {
        int nc = 64 >> tt;               // combines this step: 32,16,8,4,2
        int half = 1 << (tt - 1);
        if (tt == 1) {
#pragma unroll
            for (int r = 0; r < 2; ++r) {
                int j = pg + r * 16;
                int r0 = j << 1;
                float4 k0 = *(const float4*)(rk + r0 * 64 + sub * 4);
                float4 k1 = *(const float4*)(rk + (r0 + 1) * 64 + sub * 4);
                float4 v0 = *(const float4*)(rv + r0 * 64 + sub * 4);
                float4 v1 = *(const float4*)(rv + (r0 + 1) * 64 + sub * 4);
                float4 kp, vp;
                combine(k0, k1, v0, v1, kp, vp);
                *(float4*)(rk + r0 * 64 + sub * 4) = kp;
                *(float4*)(rv + r0 * 64 + sub * 4) = vp;
            }
        } else if (pg < nc) {
            int r0 = pg << tt;
            int r1 = r0 + half;
            float4 k0 = *(const float4*)(rk + r0 * 64 + sub * 4);
            float4 k1 = *(const float4*)(rk + r1 * 64 + sub * 4);
            float4 v0 = *(const float4*)(rv + r0 * 64 + sub * 4);
            float4 v1 = *(const float4*)(rv + r1 * 64 + sub * 4);
            float4 kp, vp;
            combine(k0, k1, v0, v1, kp, vp);
            *(float4*)(rk + r0 * 64 + sub * 4) = kp;
            *(float4*)(rv + r0 * 64 + sub * 4) = vp;
        }
        __syncthreads();
        int prow = (((c >> tt) ^ 1)) << tt;
        pkr[tt] = *(const float4*)(rk + prow * 64 + sub * 4);
        pvr[tt] = *(const float4*)(rv + prow * 64 + sub * 4);
        __syncthreads();
    }

    // ---- Phase C: rebuild in-chunk tree levels 1..5 into the same LDS ----
    // layout: rows 0..31 = l1, 32..47 = l2, 48..55 = l3, 56..59 = l4, 60..61 = l5
#pragma unroll
    for (int r = 0; r < 2; ++r) {
        int j = pg + r * 16;
        int s0 = c * 64 + 2 * j;
        size_t a0 = ((((size_t)b * S + s0) * H + h) * D) + sub * 4;
        float4 k0 = *(const float4*)(k + a0);
        float4 k1 = *(const float4*)(k + a0 + H * D);
        float4 v0 = *(const float4*)(v + a0);
        float4 v1 = *(const float4*)(v + a0 + H * D);
        float4 kp, vp;
        combine(k0, k1, v0, v1, kp, vp);
        *(float4*)(rk + j * 64 + sub * 4) = kp;
        *(float4*)(rv + j * 64 + sub * 4) = vp;
    }
    __syncthreads();
    {
        int srcOff = 0, dstOff = 32, np = 16;
#pragma unroll
        for (int l = 2; l <= 5; ++l) {
            if (pg < np) {
                int j = pg;
                float4 k0 = *(const float4*)(rk + (srcOff + 2 * j) * 64 + sub * 4);
                float4 k1 = *(const float4*)(rk + (srcOff + 2 * j + 1) * 64 + sub * 4);
                float4 v0 = *(const float4*)(rv + (srcOff + 2 * j) * 64 + sub * 4);
                float4 v1 = *(const float4*)(rv + (srcOff + 2 * j + 1) * 64 + sub * 4);
                float4 kp, vp;
                combine(k0, k1, v0, v1, kp, vp);
                *(float4*)(rk + (dstOff + j) * 64 + sub * 4) = kp;
                *(float4*)(rv + (dstOff + j) * 64 + sub * 4) = vp;
            }
            __syncthreads();
            srcOff = dstOff; dstOff += np; np >>= 1;
        }
    }

    // ---- Phase D: scoring; group pg handles queries sl = pg + 16r ----
#pragma unroll 2
    for (int r = 0; r < 4; ++r) {
        int sl = pg + r * 16;
        int s = c * 64 + sl;
        size_t qa = ((((size_t)b * S + s) * H + h) * D) + sub * 4;
        float4 q4 = *(const float4*)(q + qa);
        float4 k4 = *(const float4*)(k + qa);
        float4 v4 = *(const float4*)(v + qa);

        float ss = red16(dot4(q4, k4)) * SCALE;

        float sc[12];
        float4 vc0 = v4;                 // dummy init (guarded by odd)
        const bool odd = (s & 1) != 0;
        if (odd) {
            float4 kc0 = *(const float4*)(k + qa - H * D);
            vc0 = *(const float4*)(v + qa - H * D);
            sc[0] = red16(dot4(q4, kc0)) * SCALE;
        } else {
            sc[0] = -1e38f;
        }
#pragma unroll
        for (int l = 1; l <= 5; ++l) {
            if ((s >> l) & 1) {
                int base = 64 - (64 >> (l - 1));          // 0,32,48,56,60
                int loc = base + (((s >> l) ^ 1) - (c << (6 - l)));
                float4 kc = *(const float4*)(rk + loc * 64 + sub * 4);
                sc[l] = red16(dot4(q4, kc)) * SCALE;
            } else sc[l] = -1e38f;
        }
#pragma unroll
        for (int l = 6; l <= 11; ++l) {
            if ((c >> (l - 6)) & 1) {                     // == bit l of s
                sc[l] = red16(dot4(q4, pkr[l - 6])) * SCALE;
            } else sc[l] = -1e38f;
        }

        float m = ss;
#pragma unroll
        for (int l = 0; l < 12; ++l) m = fmaxf(m, sc[l]);

        float es = __expf(ss - m);
        float denom = es;
        float4 acc;
        acc.x = es * v4.x; acc.y = es * v4.y; acc.z = es * v4.z; acc.w = es * v4.w;

        if (odd) {
            float e = __expf(sc[0] - m);
            denom += e;
            acc.x += e * vc0.x; acc.y += e * vc0.y;
            acc.z += e * vc0.z; acc.w += e * vc0.w;
        }
#pragma unroll
        for (int l = 1; l <= 5; ++l) {
            if ((s >> l) & 1) {
                int base = 64 - (64 >> (l - 1));
                int loc = base + (((s >> l) ^ 1) - (c << (6 - l)));
                float4 vc = *(const float4*)(rv + loc * 64 + sub * 4);
                float e = __expf(sc[l] - m);
                denom += e;
                acc.x += e * vc.x; acc.y += e * vc.y;
                acc.z += e * vc.z; acc.w += e * vc.w;
            }
        }
#pragma unroll
        for (int l = 6; l <= 11; ++l) {
            if ((c >> (l - 6)) & 1) {
                float e = __expf(sc[l] - m);
                denom += e;
                acc.x += e * pvr[l - 6].x; acc.y += e * pvr[l - 6].y;
                acc.z += e * pvr[l - 6].z; acc.w += e * pvr[l - 6].w;
            }
        }
        float inv = 1.0f / denom;
        float4 o;
        o.x = acc.x * inv; o.y = acc.y * inv;
        o.z = acc.z * inv; o.w = acc.w * inv;
        *(float4*)(out + qa) = o;
    }
}

extern "C" void kernel_launch(void* const* d_in, const int* in_sizes, int n_in,
                              void* d_out, int out_size, void* d_ws, size_t ws_size,
                              hipStream_t stream) {
    const float* q = (const float*)d_in[0];
    const float* k = (const float*)d_in[1];
    const float* v = (const float*)d_in[2];
    float* outp = (float*)d_out;
    float* khi = (float*)d_ws;                      // 32*64*64 f32 = 512 KB
    float* vhi = khi + (size_t)NBH * 64 * D;

    hipLaunchKernelGGL(chunk_root, dim3(NBH * 64), dim3(256), 0, stream,
                       k, v, khi, vhi);
    hipLaunchKernelGGL(attn_fused, dim3(NBH * 64), dim3(256), 0, stream,
                       q, k, v, khi, vhi, outp);
}

// Round 4
// 166.859 us; speedup vs baseline: 1.0164x; 1.0164x over previous
//
#include <hip/hip_runtime.h>

// Hierarchical sparse attention (binary tree), MI355X gfx950.
// B=4, S=4096, H=8, D=64, f32.
//
// v5: occupancy-focused restructure (latency-bound diagnosis: 2 TB/s, 31%
// VALU, 33% occupancy at 32 KB LDS).
//  K1 chunk5: per (bh, pair of 32-leaf chunks) build levels 1..5 in LDS,
//     write the level-5 root (one per 32-chunk, 128 per bh).
//  K2 build_hi: per bh, levels 6..11 from the 128 level-5 roots.
//     hi layout per bh (NHI=254 rows): [0,128)=l5, [128,192)=l6,
//     [192,224)=l7, [224,240)=l8, [240,248)=l9, [248,252)=l10, [252,254)=l11.
//  K3 attn32: block = (bh, 32-query chunk). In-chunk tree l1..4 (30 nodes)
//     in LDS, path nodes l5..11 staged in LDS (block-uniform). 20 KB LDS ->
//     8 blocks/CU; launch_bounds(256,8) -> VGPR<=64 -> 32 waves/CU cap.
//     Padded LDS rows (68 floats) avoid 4-way bank aliasing; query->group
//     mapping keeps low score-branch bits wave-uniform.

#define S 4096
#define H 8
#define D 64
#define B 4
#define NBH 32
#define NHI 254          // per-bh high nodes: 128+64+32+16+8+4+2 (l5..l11)
#define SCALE 0.125f
#define ROWF 68          // padded LDS row stride in floats

__device__ inline float red16(float x) {
    x += __shfl_xor(x, 1);
    x += __shfl_xor(x, 2);
    x += __shfl_xor(x, 4);
    x += __shfl_xor(x, 8);
    return x;
}

__device__ inline float dot4(const float4 a, const float4 b) {
    return a.x * b.x + a.y * b.y + a.z * b.z + a.w * b.w;
}

// parent(k,v) from two children: softmax-weighted merge (16-lane reduce).
__device__ inline void combine(const float4 k0, const float4 k1,
                               const float4 v0, const float4 v1,
                               float4& kp, float4& vp) {
    kp.x = 0.5f * (k0.x + k1.x);
    kp.y = 0.5f * (k0.y + k1.y);
    kp.z = 0.5f * (k0.z + k1.z);
    kp.w = 0.5f * (k0.w + k1.w);
    float pss = red16(dot4(kp, kp)) * SCALE;
    float p0  = red16(dot4(kp, k0)) * SCALE;
    float p1  = red16(dot4(kp, k1)) * SCALE;
    float m  = fmaxf(pss, fmaxf(p0, p1));
    float es = __expf(pss - m), e0 = __expf(p0 - m), e1 = __expf(p1 - m);
    float inv = 1.0f / (es + e0 + e1 + 1e-9f);
    float h = 0.5f * es;
    vp.x = ((h + e0) * v0.x + (h + e1) * v1.x) * inv;
    vp.y = ((h + e0) * v0.y + (h + e1) * v1.y) * inv;
    vp.z = ((h + e0) * v0.z + (h + e1) * v1.z) * inv;
    vp.w = ((h + e0) * v0.w + (h + e1) * v1.w) * inv;
}

// K1: per (bh, pair of 32-leaf chunks): levels 1..5 in-place, write l5 root.
__global__ __launch_bounds__(256, 8) void chunk5(
    const float* __restrict__ k, const float* __restrict__ v,
    float* __restrict__ khi, float* __restrict__ vhi)
{
    __shared__ float lsk[32 * ROWF], lsv[32 * ROWF];   // 2 chunks x 16 rows
    const int t = threadIdx.x;
    const int sub = t & 15;
    const int pg = t >> 4;
    const int blk = blockIdx.x;
    const int pair = blk & 63;
    const int bh = blk >> 6;
    const int b = bh >> 3, h = bh & 7;
    const int csel = pg >> 3;           // 0 or 1
    const int jg = pg & 7;
    const int c = pair * 2 + csel;      // 0..127
    const int rowBase = csel * 16;

    // level 1: 16 nodes per chunk, 2 per group
#pragma unroll
    for (int r = 0; r < 2; ++r) {
        int j = jg + r * 8;
        int s0 = c * 32 + 2 * j;
        size_t a0 = ((((size_t)b * S + s0) * H + h) * D) + sub * 4;
        float4 k0 = *(const float4*)(k + a0);
        float4 k1 = *(const float4*)(k + a0 + H * D);
        float4 v0 = *(const float4*)(v + a0);
        float4 v1 = *(const float4*)(v + a0 + H * D);
        float4 kp, vp;
        combine(k0, k1, v0, v1, kp, vp);
        *(float4*)(lsk + (rowBase + j) * ROWF + sub * 4) = kp;
        *(float4*)(lsv + (rowBase + j) * ROWF + sub * 4) = vp;
    }
    __syncthreads();

    // levels 2..5 in place: after step tt, level-(1+tt) node j at row j<<tt
#pragma unroll
    for (int tt = 1; tt <= 4; ++tt) {
        int nodes = 16 >> tt;            // 8,4,2,1
        for (int j = jg; j < nodes; j += 8) {
            int r0 = rowBase + ((2 * j) << (tt - 1));
            int r1 = rowBase + ((2 * j + 1) << (tt - 1));
            float4 k0 = *(const float4*)(lsk + r0 * ROWF + sub * 4);
            float4 k1 = *(const float4*)(lsk + r1 * ROWF + sub * 4);
            float4 v0 = *(const float4*)(lsv + r0 * ROWF + sub * 4);
            float4 v1 = *(const float4*)(lsv + r1 * ROWF + sub * 4);
            float4 kp, vp;
            combine(k0, k1, v0, v1, kp, vp);
            if (tt < 4) {
                *(float4*)(lsk + (rowBase + (j << tt)) * ROWF + sub * 4) = kp;
                *(float4*)(lsv + (rowBase + (j << tt)) * ROWF + sub * 4) = vp;
            } else {
                size_t g = ((size_t)bh * NHI + c) * 64 + sub * 4;
                *(float4*)(khi + g) = kp;
                *(float4*)(vhi + g) = vp;
            }
        }
        __syncthreads();
    }
}

// K2: per bh, build levels 6..11 from the 128 level-5 roots.
__global__ __launch_bounds__(256) void build_hi(
    float* __restrict__ khi, float* __restrict__ vhi)
{
    __shared__ float lk[128 * ROWF], lv[128 * ROWF];   // ~34.8 KB each
    const int t = threadIdx.x;
    const int sub = t & 15;
    const int pg = t >> 4;
    const int bh = blockIdx.x;
    size_t base = (size_t)bh * NHI * 64;

    for (int i = t; i < 2048; i += 256) {
        int row = i >> 4, s16 = i & 15;
        *(float4*)(lk + row * ROWF + s16 * 4) = *(const float4*)(khi + base + i * 4);
        *(float4*)(lv + row * ROWF + s16 * 4) = *(const float4*)(vhi + base + i * 4);
    }
    __syncthreads();

#pragma unroll
    for (int tt = 1; tt <= 6; ++tt) {
        int nodes = 128 >> tt;               // 64,32,16,8,4,2
        int off = 256 - (256 >> tt);         // 128,192,224,240,248,252
        for (int j = pg; j < nodes; j += 16) {
            int r0 = (2 * j) << (tt - 1);
            int r1 = (2 * j + 1) << (tt - 1);
            float4 k0 = *(const float4*)(lk + r0 * ROWF + sub * 4);
            float4 k1 = *(const float4*)(lk + r1 * ROWF + sub * 4);
            float4 v0 = *(const float4*)(lv + r0 * ROWF + sub * 4);
            float4 v1 = *(const float4*)(lv + r1 * ROWF + sub * 4);
            float4 kp, vp;
            combine(k0, k1, v0, v1, kp, vp);
            *(float4*)(lk + (j << tt) * ROWF + sub * 4) = kp;
            *(float4*)(lv + (j << tt) * ROWF + sub * 4) = vp;
            size_t g = base + (size_t)(off + j) * 64 + sub * 4;
            *(float4*)(khi + g) = kp;
            *(float4*)(vhi + g) = vp;
        }
        __syncthreads();
    }
}

// K3: attention. Block = (bh, 32-query chunk). Tree l1..4 + path l5..11 in LDS.
__global__ __launch_bounds__(256, 8) void attn32(
    const float* __restrict__ q, const float* __restrict__ k,
    const float* __restrict__ v,
    const float* __restrict__ khi, const float* __restrict__ vhi,
    float* __restrict__ out)
{
    __shared__ float tk[30 * ROWF], tv[30 * ROWF];   // l1:0-15 l2:16-23 l3:24-27 l4:28-29
    __shared__ float pk[7 * ROWF], pv[7 * ROWF];     // path l5..11
    const int t = threadIdx.x;
    const int sub = t & 15;
    const int pg = t >> 4;
    const int blk = blockIdx.x;
    const int c32 = blk & 127;
    const int bh = blk >> 7;
    const int b = bh >> 3, h = bh & 7;

    // stage path nodes (block-uniform): groups 0..6 -> pk, 8..14 -> pv
    {
        int pl = (pg < 7) ? pg : pg - 8;
        if (pl >= 0 && pl < 7 && pg != 7 && pg != 15) {
            if ((c32 >> pl) & 1) {
                int off = 256 - (256 >> pl);     // 0,128,192,224,240,248,252
                int node = off + ((c32 >> pl) ^ 1);
                size_t a = ((size_t)bh * NHI + node) * 64 + sub * 4;
                if (pg < 7) *(float4*)(pk + pl * ROWF + sub * 4) = *(const float4*)(khi + a);
                else        *(float4*)(pv + pl * ROWF + sub * 4) = *(const float4*)(vhi + a);
            }
        }
    }

    // in-chunk tree level 1: 16 nodes, one per group
    {
        int j = pg;
        int s0 = c32 * 32 + 2 * j;
        size_t a0 = ((((size_t)b * S + s0) * H + h) * D) + sub * 4;
        float4 k0 = *(const float4*)(k + a0);
        float4 k1 = *(const float4*)(k + a0 + H * D);
        float4 v0 = *(const float4*)(v + a0);
        float4 v1 = *(const float4*)(v + a0 + H * D);
        float4 kp, vp;
        combine(k0, k1, v0, v1, kp, vp);
        *(float4*)(tk + j * ROWF + sub * 4) = kp;
        *(float4*)(tv + j * ROWF + sub * 4) = vp;
    }
    __syncthreads();
    // level 2: 8 nodes -> rows 16..23
    if (pg < 8) {
        int j = pg;
        float4 k0 = *(const float4*)(tk + (2 * j) * ROWF + sub * 4);
        float4 k1 = *(const float4*)(tk + (2 * j + 1) * ROWF + sub * 4);
        float4 v0 = *(const float4*)(tv + (2 * j) * ROWF + sub * 4);
        float4 v1 = *(const float4*)(tv + (2 * j + 1) * ROWF + sub * 4);
        float4 kp, vp;
        combine(k0, k1, v0, v1, kp, vp);
        *(float4*)(tk + (16 + j) * ROWF + sub * 4) = kp;
        *(float4*)(tv + (16 + j) * ROWF + sub * 4) = vp;
    }
    __syncthreads();
    // level 3: 4 nodes -> rows 24..27
    if (pg < 4) {
        int j = pg;
        float4 k0 = *(const float4*)(tk + (16 + 2 * j) * ROWF + sub * 4);
        float4 k1 = *(const float4*)(tk + (16 + 2 * j + 1) * ROWF + sub * 4);
        float4 v0 = *(const float4*)(tv + (16 + 2 * j) * ROWF + sub * 4);
        float4 v1 = *(const float4*)(tv + (16 + 2 * j + 1) * ROWF + sub * 4);
        float4 kp, vp;
        combine(k0, k1, v0, v1, kp, vp);
        *(float4*)(tk + (24 + j) * ROWF + sub * 4) = kp;
        *(float4*)(tv + (24 + j) * ROWF + sub * 4) = vp;
    }
    __syncthreads();
    // level 4: 2 nodes -> rows 28..29
    if (pg < 2) {
        int j = pg;
        float4 k0 = *(const float4*)(tk + (24 + 2 * j) * ROWF + sub * 4);
        float4 k1 = *(const float4*)(tk + (24 + 2 * j + 1) * ROWF + sub * 4);
        float4 v0 = *(const float4*)(tv + (24 + 2 * j) * ROWF + sub * 4);
        float4 v1 = *(const float4*)(tv + (24 + 2 * j + 1) * ROWF + sub * 4);
        float4 kp, vp;
        combine(k0, k1, v0, v1, kp, vp);
        *(float4*)(tk + (28 + j) * ROWF + sub * 4) = kp;
        *(float4*)(tv + (28 + j) * ROWF + sub * 4) = vp;
    }
    __syncthreads();

    // scoring: group pg -> queries sl = (pg>>2) + (pg&3)*4 + 16r
    // (keeps s&3 wave-uniform -> l0/l1 branches wave-uniform)
#pragma unroll 1
    for (int r = 0; r < 2; ++r) {
        int sl = (pg >> 2) + (pg & 3) * 4 + r * 16;
        int s = c32 * 32 + sl;
        size_t qa = ((((size_t)b * S + s) * H + h) * D) + sub * 4;
        float4 q4 = *(const float4*)(q + qa);
        float4 k4 = *(const float4*)(k + qa);
        float4 v4 = *(const float4*)(v + qa);

        float ss = red16(dot4(q4, k4)) * SCALE;

        float sc[12];
        float4 vc0 = v4;                 // dummy init (guarded by odd)
        const bool odd = (s & 1) != 0;
        if (odd) {
            float4 kc0 = *(const float4*)(k + qa - H * D);
            vc0 = *(const float4*)(v + qa - H * D);
            sc[0] = red16(dot4(q4, kc0)) * SCALE;
        } else {
            sc[0] = -1e38f;
        }
#pragma unroll
        for (int l = 1; l <= 4; ++l) {
            if ((s >> l) & 1) {
                int base = 32 - (32 >> (l - 1));          // 0,16,24,28
                int loc = base + (((s >> l) ^ 1) - (c32 << (5 - l)));
                float4 kc = *(const float4*)(tk + loc * ROWF + sub * 4);
                sc[l] = red16(dot4(q4, kc)) * SCALE;
            } else sc[l] = -1e38f;
        }
#pragma unroll
        for (int l = 5; l <= 11; ++l) {
            if ((c32 >> (l - 5)) & 1) {                   // == bit l of s
                float4 kc = *(const float4*)(pk + (l - 5) * ROWF + sub * 4);
                sc[l] = red16(dot4(q4, kc)) * SCALE;
            } else sc[l] = -1e38f;
        }

        float m = ss;
#pragma unroll
        for (int l = 0; l < 12; ++l) m = fmaxf(m, sc[l]);

        float es = __expf(ss - m);
        float denom = es;
        float4 acc;
        acc.x = es * v4.x; acc.y = es * v4.y;
        acc.z = es * v4.z; acc.w = es * v4.w;

        if (odd) {
            float e = __expf(sc[0] - m);
            denom += e;
            acc.x += e * vc0.x; acc.y += e * vc0.y;
            acc.z += e * vc0.z; acc.w += e * vc0.w;
        }
#pragma unroll
        for (int l = 1; l <= 4; ++l) {
            if ((s >> l) & 1) {
                int base = 32 - (32 >> (l - 1));
                int loc = base + (((s >> l) ^ 1) - (c32 << (5 - l)));
                float4 vc = *(const float4*)(tv + loc * ROWF + sub * 4);
                float e = __expf(sc[l] - m);
                denom += e;
                acc.x += e * vc.x; acc.y += e * vc.y;
                acc.z += e * vc.z; acc.w += e * vc.w;
            }
        }
#pragma unroll
        for (int l = 5; l <= 11; ++l) {
            if ((c32 >> (l - 5)) & 1) {
                float4 vc = *(const float4*)(pv + (l - 5) * ROWF + sub * 4);
                float e = __expf(sc[l] - m);
                denom += e;
                acc.x += e * vc.x; acc.y += e * vc.y;
                acc.z += e * vc.z; acc.w += e * vc.w;
            }
        }
        float inv = 1.0f / denom;
        float4 o;
        o.x = acc.x * inv; o.y = acc.y * inv;
        o.z = acc.z * inv; o.w = acc.w * inv;
        *(float4*)(out + qa) = o;
    }
}

extern "C" void kernel_launch(void* const* d_in, const int* in_sizes, int n_in,
                              void* d_out, int out_size, void* d_ws, size_t ws_size,
                              hipStream_t stream) {
    const float* q = (const float*)d_in[0];
    const float* k = (const float*)d_in[1];
    const float* v = (const float*)d_in[2];
    float* outp = (float*)d_out;
    float* khi = (float*)d_ws;                      // 32*254*64 f32 ~= 2.1 MB
    float* vhi = khi + (size_t)NBH * NHI * D;

    hipLaunchKernelGGL(chunk5, dim3(NBH * 64), dim3(256), 0, stream,
                       k, v, khi, vhi);
    hipLaunchKernelGGL(build_hi, dim3(NBH), dim3(256), 0, stream, khi, vhi);
    hipLaunchKernelGGL(attn32, dim3(NBH * 128), dim3(256), 0, stream,
                       q, k, v, khi, vhi, outp);
}